// Round 17
// baseline (158.441 us; speedup 1.0000x reference)
//
#include <hip/hip_runtime.h>

#define BATCH 32
#define CH    256
#define HWPX  3136   // 56*56
#define WIDTH 56
#define NK    16
#define NT    49     // pixel tiles per batch (64 px each)
#define WGTS  52     // wgt row stride (49 padded to 13*float4)
#define EPSV  1e-5f

// ---------------------------------------------------------------------------
// Kernel 1 (fused kkvec+ksum+kpmat): per (b, 64-px tile):
//   stage xn tile -> LDS; K-tile = kw @ xn (LDS only); Pp partial = xn @ K.
// R13-R16 lesson: contiguous 512B wave-loads cap at ~2TB/s no matter the
// depth; kpmat's channel-scattered float4 pattern (64 lines/instr) runs ~2x
// faster -> stage with THAT pattern, read x ONCE, and never write K to HBM
// (saves x re-read 103MB + K round-trip ~100MB).
// LDS: s_x[256][65] (pad: stage writes lane-consecutive banks; K-phase reads
// fixed-c consecutive; P-phase reads stride-65 = 2-way free). s_K[k][px]
// (writes lane-consecutive; reads uniform float4 broadcast). 70.6KB -> 2
// blocks/CU; the two resident blocks' stage/compute phases interleave.
// ---------------------------------------------------------------------------
__global__ __launch_bounds__(256) void kfuse(
    const float* __restrict__ x,
    const float* __restrict__ gamma, const float* __restrict__ beta,
    const float* __restrict__ mean,  const float* __restrict__ var,
    const float* __restrict__ kw,    float* __restrict__ Pp)
{
    const int b   = blockIdx.x / NT;
    const int t   = blockIdx.x % NT;
    const int n0  = t * 64;
    const int tid = threadIdx.x;

    __shared__ float s_x[CH * 65];     // 66,560 B
    __shared__ float s_K[NK * 64];     //  4,096 B

    // ---- stage: thread = channel; 16 scattered float4 loads deep ----
    {
        const int c = tid;
        const float sc = gamma[c] * rsqrtf(var[c] + EPSV);
        const float sh = fmaf(-mean[c], sc, beta[c]);
        const float4* xr = (const float4*)(x + ((size_t)b * CH + c) * HWPX + n0);
        float* dst = s_x + c * 65;
#pragma unroll
        for (int j = 0; j < 16; ++j) {
            const float4 v = xr[j];
            dst[4*j+0] = fmaf(v.x, sc, sh);
            dst[4*j+1] = fmaf(v.y, sc, sh);
            dst[4*j+2] = fmaf(v.z, sc, sh);
            dst[4*j+3] = fmaf(v.w, sc, sh);
        }
    }
    __syncthreads();

    // ---- K tile: wave = k-quad (uniform), lane = pixel ----
    {
        const int w = tid >> 6;        // 0..3, wave-uniform
        const int p = tid & 63;
        float ka[4] = {0.f, 0.f, 0.f, 0.f};
#pragma unroll 4
        for (int c = 0; c < CH; c += 4) {
            const float xv0 = s_x[(c+0)*65 + p];   // consecutive lanes -> consecutive banks
            const float xv1 = s_x[(c+1)*65 + p];
            const float xv2 = s_x[(c+2)*65 + p];
            const float xv3 = s_x[(c+3)*65 + p];
#pragma unroll
            for (int i = 0; i < 4; ++i) {
                const float4 k4 = *(const float4*)(kw + (4*w+i)*CH + c);  // uniform -> s_load
                ka[i] = fmaf(xv0, k4.x, ka[i]);
                ka[i] = fmaf(xv1, k4.y, ka[i]);
                ka[i] = fmaf(xv2, k4.z, ka[i]);
                ka[i] = fmaf(xv3, k4.w, ka[i]);
            }
        }
#pragma unroll
        for (int i = 0; i < 4; ++i) s_K[(4*w+i)*64 + p] = ka[i];  // lane-consecutive
    }
    __syncthreads();

    // ---- P partial: thread = channel; K via uniform float4 broadcast ----
    {
        const int c = tid;
        float acc[NK];
#pragma unroll
        for (int k = 0; k < NK; ++k) acc[k] = 0.f;
        const float* xrowp = s_x + c * 65;
#pragma unroll
        for (int j0 = 0; j0 < 64; j0 += 16) {
            float xr_[16];
#pragma unroll
            for (int j = 0; j < 16; ++j) xr_[j] = xrowp[j0 + j];  // stride-65: 2-way, free
#pragma unroll
            for (int k = 0; k < NK; ++k) {
#pragma unroll
                for (int q = 0; q < 4; ++q) {
                    const float4 kv = *(const float4*)(s_K + k*64 + j0 + 4*q);  // broadcast
                    acc[k] = fmaf(xr_[4*q+0], kv.x, acc[k]);
                    acc[k] = fmaf(xr_[4*q+1], kv.y, acc[k]);
                    acc[k] = fmaf(xr_[4*q+2], kv.z, acc[k]);
                    acc[k] = fmaf(xr_[4*q+3], kv.w, acc[k]);
                }
            }
        }
        float* op = Pp + (((size_t)b * NT + t) * CH + c) * NK;   // 64B/lane contiguous
#pragma unroll
        for (int kq = 0; kq < 4; ++kq)
            ((float4*)op)[kq] = make_float4(acc[kq*4+0], acc[kq*4+1], acc[kq*4+2], acc[kq*4+3]);
    }
}

// ---------------------------------------------------------------------------
// Kernel 2: reduce tile partials Pp[b][NT][CH*NK] -> P[b][CH*NK]
// ---------------------------------------------------------------------------
__global__ __launch_bounds__(256) void kpred(
    const float* __restrict__ Pp, float* __restrict__ P)
{
    const int idx = blockIdx.x * 256 + threadIdx.x;   // 32*4096 total
    const int b = idx >> 12;
    const int e = idx & 4095;
    const float* p = Pp + (size_t)b * NT * 4096 + e;
    float s = 0.f;
#pragma unroll
    for (int t = 0; t < NT; ++t) s += p[(size_t)t * 4096];
    P[idx] = s;
}

// ---------------------------------------------------------------------------
// Kernel 3: S = q_w @ P; attn = softmax(S/512) over k; wgt = attn @ bank.
// wgt rows padded to 52 floats (16B-aligned float4 reads in kconv).
// ---------------------------------------------------------------------------
__global__ __launch_bounds__(256) void ksoft(
    const float* __restrict__ P, const float* __restrict__ qw,
    const float* __restrict__ bank, float* __restrict__ wgt)
{
    const int b  = blockIdx.x >> 3;
    const int cb = blockIdx.x & 7;
    const int tid = threadIdx.x;

    __shared__ float s_P[CH * NK];       // full P[b] (16 KB)
    __shared__ float s_red[32 * 8 * NK]; // partial S (16 KB)
    __shared__ float s_S[32 * NK];
    __shared__ float s_attn[32 * NK];

    for (int idx = tid; idx < CH * NK; idx += 256)
        s_P[idx] = P[(size_t)b * CH * NK + idx];
    __syncthreads();

    const int c_l = tid & 31, sub = tid >> 5;
    const int c = cb * 32 + c_l;
    float a[NK];
#pragma unroll
    for (int k = 0; k < NK; ++k) a[k] = 0.f;
    const float* qrow = qw + (size_t)c * CH + sub * 32;
    for (int j = 0; j < 32; ++j) {
        const float qv = qrow[j];
        const float4* p4 = (const float4*)&s_P[(sub * 32 + j) * NK];
#pragma unroll
        for (int kq = 0; kq < 4; ++kq) {
            const float4 pv = p4[kq];
            a[kq*4+0] = fmaf(qv, pv.x, a[kq*4+0]);
            a[kq*4+1] = fmaf(qv, pv.y, a[kq*4+1]);
            a[kq*4+2] = fmaf(qv, pv.z, a[kq*4+2]);
            a[kq*4+3] = fmaf(qv, pv.w, a[kq*4+3]);
        }
    }
#pragma unroll
    for (int kq = 0; kq < 4; ++kq)
        *(float4*)&s_red[(c_l * 8 + sub) * NK + kq*4] =
            make_float4(a[kq*4+0], a[kq*4+1], a[kq*4+2], a[kq*4+3]);
    __syncthreads();

    for (int idx = tid; idx < 32 * NK; idx += 256) {
        const int cl = idx >> 4, k = idx & 15;
        float s = 0.f;
#pragma unroll
        for (int s2 = 0; s2 < 8; ++s2) s += s_red[(cl * 8 + s2) * NK + k];
        s_S[idx] = s * (1.f / 512.f);
    }
    __syncthreads();

    if (tid < 32) {
        float l[NK];
#pragma unroll
        for (int k = 0; k < NK; ++k) l[k] = s_S[tid * NK + k];
        float m = l[0];
#pragma unroll
        for (int k = 1; k < NK; ++k) m = fmaxf(m, l[k]);
        float sum = 0.f;
#pragma unroll
        for (int k = 0; k < NK; ++k) { l[k] = __expf(l[k] - m); sum += l[k]; }
        const float inv = 1.f / sum;
#pragma unroll
        for (int k = 0; k < NK; ++k) s_attn[tid * NK + k] = l[k] * inv;
    }
    __syncthreads();

    for (int idx = tid; idx < 32 * 49; idx += 256) {
        const int cl = idx / 49, e = idx - cl * 49;
        float wv = 0.f;
#pragma unroll
        for (int k = 0; k < NK; ++k)
            wv = fmaf(s_attn[cl * NK + k], bank[k * 49 + e], wv);
        wgt[((size_t)b * CH + cb * 32 + cl) * WGTS + e] = wv;
    }
}

// ---------------------------------------------------------------------------
// Kernel 4: depthwise 7x7 'same' conv — zero-LDS, shuffle-halo line buffer.
// (R10-fixed: no min-waves arg -> no VGPR cap -> no spill.)
// Slot schedule (R9-verified): reset slot j%7 at TOP of iteration j.
// ---------------------------------------------------------------------------
__global__ __launch_bounds__(256) void kconv(
    const float* __restrict__ x, const float* __restrict__ wgt,
    const float* __restrict__ bias, float* __restrict__ out)
{
    const int t  = threadIdx.x;          // 0..255
    const int pl = t >> 4;               // 0..15 local plane
    const int q  = t & 15;               // 0..15 strip slot (14 valid)
    const int qc = q < 14 ? q : 13;      // clamped col chunk for idle lanes
    const int h  = blockIdx.x & 1;       // y-half
    const int plane = (blockIdx.x >> 1) * 16 + pl;
    const int ho = h * 28;               // first output row (0 or 28; ==0 mod 7)
    const bool qlo = (q == 0), qhi = (q >= 13);
    const float bv = bias[plane & 255];

    float4 wv[13];
    const float4* wp4 = (const float4*)(wgt + (size_t)plane * WGTS);
#pragma unroll
    for (int i = 0; i < 13; ++i) wv[i] = wp4[i];
#define WTAP(idx) ((idx)%4==0 ? wv[(idx)/4].x : (idx)%4==1 ? wv[(idx)/4].y : \
                   (idx)%4==2 ? wv[(idx)/4].z : wv[(idx)/4].w)

    const float* xrow = x   + (size_t)plane * HWPX + 4 * qc;
    float*       orow = out + (size_t)plane * HWPX + 4 * qc;

    float a[7][4];
#pragma unroll
    for (int i = 0; i < 7; ++i)
#pragma unroll
        for (int ix = 0; ix < 4; ++ix) a[i][ix] = bv;

    const float4 z4 = make_float4(0.f, 0.f, 0.f, 0.f);
    int ir0 = ho - 3;
    float4 vc = (0 <= ir0 && ir0 < 56) ? *(const float4*)(xrow + ir0 * WIDTH) : z4;

#pragma unroll 7
    for (int j = 0; j < 35; ++j) {
        const int snew = j % 7;                  // static under unroll 7
#pragma unroll
        for (int ix = 0; ix < 4; ++ix) a[snew][ix] = bv;

        const int irn = ho - 3 + j + 1;
        float4 vn = (0 <= irn && irn < 56 && j + 1 < 35)
                        ? *(const float4*)(xrow + irn * WIDTH) : z4;

        float rr1 = __shfl_up(vc.y, 1), rr2 = __shfl_up(vc.z, 1), rr3 = __shfl_up(vc.w, 1);
        float rr8 = __shfl_down(vc.x, 1), rr9 = __shfl_down(vc.y, 1), rr10 = __shfl_down(vc.z, 1);
        float rr[11];
        rr[1] = qlo ? 0.f : rr1;  rr[2] = qlo ? 0.f : rr2;  rr[3] = qlo ? 0.f : rr3;
        rr[4] = vc.x; rr[5] = vc.y; rr[6] = vc.z; rr[7] = vc.w;
        rr[8] = qhi ? 0.f : rr8;  rr[9] = qhi ? 0.f : rr9;  rr[10] = qhi ? 0.f : rr10;

#pragma unroll
        for (int i = 0; i < 7; ++i) {
            const int ky = 6 - i;
            const int s  = (j + i + 1) % 7;      // static (j%7 known by unroll)
#pragma unroll
            for (int kx = 0; kx < 7; ++kx) {
                const float wk = WTAP(ky * 7 + kx);
#pragma unroll
                for (int ix = 0; ix < 4; ++ix)
                    a[s][ix] = fmaf(wk, rr[ix + kx + 1], a[s][ix]);
            }
        }

        if (j >= 6 && j < 34) {                  // output row o = ho+j-6 done
            const int o  = ho + j - 6;
            const int sd = (j + 1) % 7;          // static; next iter resets it
            if (q < 14)
                *(float4*)(orow + o * WIDTH) =
                    make_float4(a[sd][0], a[sd][1], a[sd][2], a[sd][3]);
        }
        vc = vn;
    }
#undef WTAP
}

// ---------------------------------------------------------------------------
extern "C" void kernel_launch(void* const* d_in, const int* in_sizes, int n_in,
                              void* d_out, int out_size, void* d_ws, size_t ws_size,
                              hipStream_t stream)
{
    const float* x     = (const float*)d_in[0];
    const float* gamma = (const float*)d_in[1];
    const float* beta  = (const float*)d_in[2];
    const float* mean  = (const float*)d_in[3];
    const float* var   = (const float*)d_in[4];
    const float* qw    = (const float*)d_in[5];
    const float* kw    = (const float*)d_in[6];
    const float* bank  = (const float*)d_in[7];
    const float* bias  = (const float*)d_in[8];
    float* out = (float*)d_out;

    // ws layout (~28 MB): Pp | P | wgt   (no K buffers anymore)
    float* ws  = (float*)d_ws;
    float* Pp  = ws;                                    // 32*49*4096 = 6,422,528 f
    float* P   = Pp + (size_t)BATCH * NT * CH * NK;     //   131,072 f
    float* wgt = P + (size_t)BATCH * CH * NK;           // 8192*52 = 425,984 f

    kfuse<<<dim3(BATCH * NT),   dim3(256), 0, stream>>>(x, gamma, beta, mean, var, kw, Pp);
    kpred<<<dim3(512),          dim3(256), 0, stream>>>(Pp, P);
    ksoft<<<dim3(BATCH * 8),    dim3(256), 0, stream>>>(P, qw, bank, wgt);
    kconv<<<dim3(BATCH * CH / 8), dim3(256), 0, stream>>>(x, wgt, bias, out);
}